// Round 5
// baseline (225.388 us; speedup 1.0000x reference)
//
#include <hip/hip_runtime.h>
#include <hip/hip_bf16.h>

#define NVV    40962
#define NVP    10242
#define BB     8
#define CIN    64
#define COUT   64
#define KK     7
#define EPSV   1e-5f

#define VT      64           // vertices per tile
#define NTILE   641          // ceil(NVV/VT)
#define KDIM    256          // Cin*4
#define PSTRIDE 41024        // padded pre-GN row (bf16): 82048 B = 641 x 128 B  (line-aligned!)

// d_ws layout (total ~57.2 MB):
#define CW_OFF  2048         // cW bf16 coeffs [64][256]
#define XT_OFF  36864        // xT bf16 [b][v][i] : 8*10242*64*2 = 10,487,808 B
#define PRE_OFF 10524672     // pre bf16 [row][PSTRIDE] : 512*41024*2 = 42,008,576 B (128B-aligned)
#define W4_OFF  52533248     // uint4 [NVV*KK] {idx,L,E,N} : 40962*7*16 = 4,587,744 B

typedef __attribute__((ext_vector_type(8))) short short8;
typedef __attribute__((ext_vector_type(4))) float floatx4;

__device__ __forceinline__ unsigned f2bf(float f) {
    unsigned u = __builtin_bit_cast(unsigned, f);
    return (u + 0x7FFFu + ((u >> 16) & 1u)) >> 16;    // rne (finite inputs)
}
__device__ __forceinline__ unsigned pk2(float a, float b) {   // v_cvt_pk_bf16_f32
    __hip_bfloat162 h = __float22bfloat162_rn(make_float2(a, b));
    unsigned r;
    __builtin_memcpy(&r, &h, 4);
    return r;
}
__device__ __forceinline__ float bflo(unsigned u) { return __builtin_bit_cast(float, u << 16); }
__device__ __forceinline__ float bfhi(unsigned u) { return __builtin_bit_cast(float, u & 0xffff0000u); }

// ---- transpose x -> bf16 xT[b][v][i]; zip weight quads W4; block (0,0) zeroes stats + coeffs ----
__global__ __launch_bounds__(256) void k_tr(const float* __restrict__ x,
                                            unsigned short* __restrict__ xT,
                                            const float* __restrict__ coeffs,
                                            unsigned short* __restrict__ cW,
                                            float* __restrict__ stats,
                                            const float* __restrict__ Lw,
                                            const float* __restrict__ Ew,
                                            const float* __restrict__ Nw,
                                            const int*   __restrict__ nbr,
                                            uint4* __restrict__ W4) {
    __shared__ float tile[64][65];
    const int b    = blockIdx.y;
    const int v0   = blockIdx.x * 64;
    const int lane = threadIdx.x & 63;
    const int wave = threadIdx.x >> 6;
    const int v    = v0 + lane;

    // zip {idx,L,E,N} -> one aligned 16B quad per (v,k); linear index IS v*7+k
    {
        const int gid = (blockIdx.y * 161 + blockIdx.x) * 256 + (int)threadIdx.x;
        if (gid < NVV * KK) {
            uint4 qd;
            qd.x = (unsigned)nbr[gid];
            qd.y = __builtin_bit_cast(unsigned, Lw[gid]);
            qd.z = __builtin_bit_cast(unsigned, Ew[gid]);
            qd.w = __builtin_bit_cast(unsigned, Nw[gid]);
            W4[gid] = qd;
        }
    }

    #pragma unroll
    for (int r = 0; r < 16; ++r) {
        int i = wave * 16 + r;
        tile[i][lane] = (v < NVP) ? x[((size_t)b * CIN + i) * NVP + v] : 0.f;
    }
    if (blockIdx.x == 0 && b == 0) {
        for (int t = threadIdx.x; t < 512; t += 256) stats[t] = 0.f;
        for (int t = threadIdx.x; t < COUT * KDIM; t += 256)
            cW[t] = (unsigned short)f2bf(coeffs[t]);
    }
    __syncthreads();
    const int i2 = lane & 31;
    #pragma unroll
    for (int r = 0; r < 8; ++r) {
        int vv = wave * 16 + 2 * r + (lane >> 5);
        if (v0 + vv < NVP) {
            unsigned w = pk2(tile[2 * i2][vv], tile[2 * i2 + 1][vv]);
            ((unsigned*)(xT + ((size_t)b * NVP + v0 + vv) * 64))[i2] = w;
        }
    }
}

// LDS = exactly 32768 B -> 5 blocks/CU (5*32768 = 160 KiB exactly). sred aliases Fbuf's
// tail (bytes 28672..28928), written only AFTER the post-MFMA barrier when F is dead.
// (256,5): target 5 blocks/CU; VGPR budget ~96 >= the ~68 needed (round-4: no spill at 68).
__global__ __launch_bounds__(256, 5) void k_conv(
    const unsigned short* __restrict__ xT,
    const uint4* __restrict__ W4,
    const unsigned short* __restrict__ cW,
    const float* __restrict__ bias,
    unsigned short* __restrict__ pre,
    float* __restrict__ stats)
{
    // F: 64 rows x 256 bf16 (512 B/row), XOR-swizzled in 16B groups (conflict-free)
    __shared__ unsigned short Fbuf[VT * 256];       // 32768 B; reused as float outT[64][68] + sred
    float* const sredA = (float*)(Fbuf + 14336);    // byte 28672; disjoint from outT (<=17408)

    const int bid   = blockIdx.x;
    const int b     = bid & 7;                // b <-> XCD affinity: xT[b] slab L2-resident
    const int tile  = bid >> 3;
    const int vbase = tile * VT;
    const int tid   = threadIdx.x;
    const int wave  = tid >> 6;
    const int lane  = tid & 63;
    const int q     = lane >> 4;
    const int l15   = lane & 15;

    // ---- Stage A: thread (v=lane, ch-chunk = wave*16..+16); deep gather prefetch ----
    // Weights via W4: one aligned uint4 {idx,L,E,N} per (v,k) -> 7 dwordx4 loads.
    {
        const int v  = lane;
        const int ic = wave;
        const int vg = vbase + v;

        uint4 wq[KK];
        if (vg < NVV) {
            const uint4* wp = W4 + (size_t)vg * KK;
            #pragma unroll
            for (int k = 0; k < KK; ++k) wq[k] = wp[k];
        } else {
            #pragma unroll
            for (int k = 0; k < KK; ++k) wq[k] = make_uint4(NVP, 0u, 0u, 0u);
        }
        const unsigned short* xTb = xT + (size_t)b * NVP * 64 + ic * 16;

        uint4 ga[KK], gb[KK], gu0, gu1;
        gu0 = gu1 = make_uint4(0, 0, 0, 0);
        #pragma unroll
        for (int k = 0; k < KK; ++k) { ga[k] = make_uint4(0,0,0,0); gb[k] = make_uint4(0,0,0,0); }
        if (vg < NVP) {
            const uint4* p = (const uint4*)(xTb + (size_t)vg * 64);
            gu0 = p[0]; gu1 = p[1];
        }
        #pragma unroll
        for (int k = 0; k < KK; ++k) {          // all 7 gathers issued before any use
            const int j = (int)wq[k].x;
            if (j < NVP) {
                const uint4* p = (const uint4*)(xTb + (size_t)j * 64);
                ga[k] = p[0]; gb[k] = p[1];
            }
        }

        float l[16], e[16], n[16];
        #pragma unroll
        for (int t = 0; t < 16; ++t) { l[t] = e[t] = n[t] = 0.f; }
        #pragma unroll
        for (int k = 0; k < KK; ++k) {
            const float a   = __builtin_bit_cast(float, wq[k].y);
            const float bb2 = __builtin_bit_cast(float, wq[k].z);
            const float c2  = __builtin_bit_cast(float, wq[k].w);
            const unsigned uu[8] = { ga[k].x, ga[k].y, ga[k].z, ga[k].w,
                                     gb[k].x, gb[k].y, gb[k].z, gb[k].w };
            #pragma unroll
            for (int j2 = 0; j2 < 8; ++j2) {
                float f0 = bflo(uu[j2]), f1 = bfhi(uu[j2]);   // zeros contribute 0
                l[2*j2]   = fmaf(f0, a,  l[2*j2]);   e[2*j2]   = fmaf(f0, bb2, e[2*j2]);   n[2*j2]   = fmaf(f0, c2, n[2*j2]);
                l[2*j2+1] = fmaf(f1, a,  l[2*j2+1]); e[2*j2+1] = fmaf(f1, bb2, e[2*j2+1]); n[2*j2+1] = fmaf(f1, c2, n[2*j2+1]);
            }
        }
        // pack into F: group g holds k=8g..8g+7 = ch-pair {2g,2g+1} x {u,l,e,n}
        const unsigned uup[8] = { gu0.x, gu0.y, gu0.z, gu0.w, gu1.x, gu1.y, gu1.z, gu1.w };
        #pragma unroll
        for (int jg = 0; jg < 8; ++jg) {
            const int i0 = 2 * jg;
            uint4 w;
            w.x = pk2(bflo(uup[jg]), l[i0]);        // u bf16 passthrough is exact
            w.y = pk2(e[i0],   n[i0]);
            w.z = pk2(bfhi(uup[jg]) , l[i0+1]);
            w.w = pk2(e[i0+1], n[i0+1]);
            const int g    = ic * 8 + jg;
            const int phys = g ^ (v & 31);
            *(uint4*)(Fbuf + v * 256 + phys * 8) = w;
        }
    }
    __syncthreads();

    // ---- W fragments (A-operand): lane holds A[m=l15][k=32*k0+8*q+j]; direct bf16 load ----
    short8 afrag[8];
    {
        const unsigned short* wrow = cW + (16 * wave + l15) * KDIM + q * 8;
        #pragma unroll
        for (int k0 = 0; k0 < 8; ++k0)
            afrag[k0] = *(const short8*)(wrow + k0 * 32);
    }

    // ---- MFMA: B[n=l15][k] from swizzled F ----
    floatx4 acc[4] = {{0,0,0,0},{0,0,0,0},{0,0,0,0},{0,0,0,0}};
    #pragma unroll
    for (int k0 = 0; k0 < 8; ++k0) {
        #pragma unroll
        for (int nt = 0; nt < 4; ++nt) {
            const int row  = nt * 16 + l15;
            const int phys = (k0 * 4 + q) ^ (row & 31);
            const short8 bfrag = *(const short8*)(Fbuf + row * 256 + phys * 8);
            acc[nt] = __builtin_amdgcn_mfma_f32_16x16x32_bf16(afrag[k0], bfrag, acc[nt], 0, 0, 0);
        }
    }

    // ---- Epilogue: bias, GN partial stats, bf16 pre-GN stores via LDS transpose ----
    float bs[4];
    #pragma unroll
    for (int r = 0; r < 4; ++r) bs[r] = bias[16 * wave + q * 4 + r];

    float cv[4][4];
    float sA = 0.f, s2A = 0.f, sB = 0.f, s2B = 0.f;
    #pragma unroll
    for (int nt = 0; nt < 4; ++nt) {
        const bool ok = (vbase + nt * 16 + l15 < NVV);
        #pragma unroll
        for (int r = 0; r < 4; ++r) {
            float cc = acc[nt][r] + bs[r];
            cv[nt][r] = cc;
            if (ok) {
                if (r < 2) { sA += cc; s2A = fmaf(cc, cc, s2A); }
                else       { sB += cc; s2B = fmaf(cc, cc, s2B); }
            }
        }
    }
    #pragma unroll
    for (int m = 1; m < 16; m <<= 1) {
        sA  += __shfl_xor(sA,  m);
        s2A += __shfl_xor(s2A, m);
        sB  += __shfl_xor(sB,  m);
        s2B += __shfl_xor(s2B, m);
    }
    __syncthreads();                 // F reads done; Fbuf dead -> reuse as outT + sred

    if (l15 == 0) {                  // safe: after barrier, region disjoint from outT
        float* sp = sredA + (wave * 4 + q) * 4;
        sp[0] = sA; sp[1] = s2A; sp[2] = sB; sp[3] = s2B;
    }

    float* outT = (float*)Fbuf;      // [64 o][stride 68] = 17408 B
    #pragma unroll
    for (int nt = 0; nt < 4; ++nt)
        #pragma unroll
        for (int r = 0; r < 4; ++r)
            outT[(16 * wave + 4 * q + r) * 68 + nt * 16 + l15] = cv[nt][r];
    __syncthreads();

    {   // all 64 lanes: (oo-half = lane>>5, vpair = lane&31); 2 rows x 128 B per iter
        const int oo2  = lane >> 5;
        const int vloc = 2 * (lane & 31);
        if (vbase + vloc < NVV) {    // pair {v,v+1}: both valid or both OOB (NVV even)
            unsigned short* prow = pre + (size_t)(b * COUT + 16 * wave) * PSTRIDE + vbase;
            #pragma unroll
            for (int ot = 0; ot < 8; ++ot) {
                const int oo = 2 * ot + oo2;
                float2 t = *(const float2*)(outT + (16 * wave + oo) * 68 + vloc);
                *(unsigned*)(prow + (size_t)oo * PSTRIDE + vloc) = pk2(t.x, t.y);
            }
        }
    }

    if (tid < 64) {
        const int w = tid >> 4, qq = (tid >> 2) & 3, e = tid & 3;
        const int g = 8 * w + 2 * qq + (e >> 1);
        atomicAdd(&stats[b * 64 + 2 * g + (e & 1)], sredA[(w * 4 + qq) * 4 + e]);
    }
}

// grid: 2048 blocks; blk = b + 8*(o + 64*quarter) -> blk%8==b matches k_conv's
// writer XCD (pre[b] rows live in XCD b's L2). Split-stream: read bf16 pre, write f32 out.
__global__ __launch_bounds__(256) void k_norm(
    const unsigned short* __restrict__ pre,
    float* __restrict__ out,
    const float* __restrict__ stats,
    const float* __restrict__ gamma,
    const float* __restrict__ beta)
{
    const int blk     = blockIdx.x;
    const int b       = blk & 7;
    const int rest    = blk >> 3;               // 0..255
    const int o       = rest & 63;
    const int quarter = rest >> 6;
    const int row     = b * 64 + o;
    const int g = o >> 1;
    const float inv_cnt = 1.f / (float)(2 * NVV);
    const float mean = stats[b * 64 + 2 * g] * inv_cnt;
    const float var  = fmaf(stats[b * 64 + 2 * g + 1], inv_cnt, -mean * mean);
    const float rs   = rsqrtf(var + EPSV);
    const float sc   = gamma[o] * rs;
    const float sh   = fmaf(-mean, sc, beta[o]);

    const uint4* src = (const uint4*)(pre + (size_t)row * PSTRIDE);
    float* orow = out + (size_t)row * NVV;
    #pragma unroll
    for (int it = 0; it < 5; ++it) {            // 4 quarters x 5 x 256 = 5120 uint4 = v<40960
        const int c = quarter * 1280 + it * 256 + (int)threadIdx.x;
        uint4 u = src[c];
        float f[8] = { bflo(u.x), bfhi(u.x), bflo(u.y), bfhi(u.y),
                       bflo(u.z), bfhi(u.z), bflo(u.w), bfhi(u.w) };
        float* p = orow + 8 * c;
        #pragma unroll
        for (int t = 0; t < 4; ++t) {
            float y0 = fmaf(f[2*t],   sc, sh);
            float y1 = fmaf(f[2*t+1], sc, sh);
            float2 v2 = make_float2(y0 > 0.f ? y0 : 0.f, y1 > 0.f ? y1 : 0.f);
            *(float2*)(p + 2 * t) = v2;         // 8B-aligned always
        }
    }
    if (quarter == 3 && threadIdx.x == 0) {     // tail v = 40960, 40961
        unsigned u = *(const unsigned*)(pre + (size_t)row * PSTRIDE + 40960);
        float y0 = fmaf(bflo(u), sc, sh);
        float y1 = fmaf(bfhi(u), sc, sh);
        *(float2*)(orow + 40960) = make_float2(y0 > 0.f ? y0 : 0.f, y1 > 0.f ? y1 : 0.f);
    }
}

extern "C" void kernel_launch(void* const* d_in, const int* in_sizes, int n_in,
                              void* d_out, int out_size, void* d_ws, size_t ws_size,
                              hipStream_t stream) {
    const float* x      = (const float*)d_in[0];
    const float* Lw     = (const float*)d_in[1];
    const float* Ew     = (const float*)d_in[2];
    const float* Nw     = (const float*)d_in[3];
    const float* coeffs = (const float*)d_in[4];
    const float* bias   = (const float*)d_in[5];
    const float* gamma  = (const float*)d_in[6];
    const float* beta   = (const float*)d_in[7];
    const int*   nbr    = (const int*)d_in[8];
    float* out = (float*)d_out;
    float*          stats = (float*)d_ws;
    unsigned short* cW    = (unsigned short*)((char*)d_ws + CW_OFF);
    unsigned short* xT    = (unsigned short*)((char*)d_ws + XT_OFF);
    unsigned short* pre   = (unsigned short*)((char*)d_ws + PRE_OFF);
    uint4*          W4    = (uint4*)((char*)d_ws + W4_OFF);            // needs ws >= ~57.2 MB

    k_tr<<<dim3(161, BB), dim3(256), 0, stream>>>(x, xT, coeffs, cW, stats, Lw, Ew, Nw, nbr, W4);

    k_conv<<<dim3(BB * NTILE), dim3(256), 0, stream>>>(xT, W4, cW, bias, pre, stats);

    k_norm<<<dim3(4 * BB * COUT), dim3(256), 0, stream>>>(pre, out, stats, gamma, beta);
}

// Round 6
// 205.713 us; speedup vs baseline: 1.0956x; 1.0956x over previous
//
#include <hip/hip_runtime.h>
#include <hip/hip_bf16.h>

#define NVV    40962
#define NVP    10242
#define BB     8
#define CIN    64
#define COUT   64
#define KK     7
#define EPSV   1e-5f

#define VT      64           // vertices per tile
#define NTILE   641          // ceil(NVV/VT)
#define KDIM    256          // Cin*4
#define PSTRIDE 41024        // padded pre-GN row (bf16): 82048 B = 641 x 128 B  (line-aligned!)

// d_ws layout (total ~57.2 MB):
#define CW_OFF  2048         // cW bf16 coeffs [64][256]
#define XT_OFF  36864        // xT bf16 [b][v][i] : 8*10242*64*2 = 10,487,808 B
#define PRE_OFF 10524672     // pre bf16 [row][PSTRIDE] : 512*41024*2 = 42,008,576 B (128B-aligned)
#define W4_OFF  52533248     // uint4 [NVV*KK] {idx,L,E,N} : 40962*7*16 = 4,587,744 B

typedef __attribute__((ext_vector_type(8))) short short8;
typedef __attribute__((ext_vector_type(4))) float floatx4;

__device__ __forceinline__ unsigned f2bf(float f) {
    unsigned u = __builtin_bit_cast(unsigned, f);
    return (u + 0x7FFFu + ((u >> 16) & 1u)) >> 16;    // rne (finite inputs)
}
__device__ __forceinline__ unsigned pk2(float a, float b) {   // v_cvt_pk_bf16_f32
    __hip_bfloat162 h = __float22bfloat162_rn(make_float2(a, b));
    unsigned r;
    __builtin_memcpy(&r, &h, 4);
    return r;
}
__device__ __forceinline__ float bflo(unsigned u) { return __builtin_bit_cast(float, u << 16); }
__device__ __forceinline__ float bfhi(unsigned u) { return __builtin_bit_cast(float, u & 0xffff0000u); }

// ---- transpose x -> bf16 xT[b][v][i]; zip weight quads W4; block (0,0) zeroes stats + coeffs ----
__global__ __launch_bounds__(256) void k_tr(const float* __restrict__ x,
                                            unsigned short* __restrict__ xT,
                                            const float* __restrict__ coeffs,
                                            unsigned short* __restrict__ cW,
                                            float* __restrict__ stats,
                                            const float* __restrict__ Lw,
                                            const float* __restrict__ Ew,
                                            const float* __restrict__ Nw,
                                            const int*   __restrict__ nbr,
                                            uint4* __restrict__ W4) {
    __shared__ float tile[64][65];
    const int b    = blockIdx.y;
    const int v0   = blockIdx.x * 64;
    const int lane = threadIdx.x & 63;
    const int wave = threadIdx.x >> 6;
    const int v    = v0 + lane;

    // zip {idx,L,E,N} -> one aligned 16B quad per (v,k); linear index IS v*7+k
    {
        const int gid = (blockIdx.y * 161 + blockIdx.x) * 256 + (int)threadIdx.x;
        if (gid < NVV * KK) {
            uint4 qd;
            qd.x = (unsigned)nbr[gid];
            qd.y = __builtin_bit_cast(unsigned, Lw[gid]);
            qd.z = __builtin_bit_cast(unsigned, Ew[gid]);
            qd.w = __builtin_bit_cast(unsigned, Nw[gid]);
            W4[gid] = qd;
        }
    }

    #pragma unroll
    for (int r = 0; r < 16; ++r) {
        int i = wave * 16 + r;
        tile[i][lane] = (v < NVP) ? x[((size_t)b * CIN + i) * NVP + v] : 0.f;
    }
    if (blockIdx.x == 0 && b == 0) {
        for (int t = threadIdx.x; t < 512; t += 256) stats[t] = 0.f;
        for (int t = threadIdx.x; t < COUT * KDIM; t += 256)
            cW[t] = (unsigned short)f2bf(coeffs[t]);
    }
    __syncthreads();
    const int i2 = lane & 31;
    #pragma unroll
    for (int r = 0; r < 8; ++r) {
        int vv = wave * 16 + 2 * r + (lane >> 5);
        if (v0 + vv < NVP) {
            unsigned w = pk2(tile[2 * i2][vv], tile[2 * i2 + 1][vv]);
            ((unsigned*)(xT + ((size_t)b * NVP + v0 + vv) * 64))[i2] = w;
        }
    }
}

// (256,4): empirically the fastest point (r0 vs r4 vs r5): 64-VGPR cap + ~4 blocks/CU.
// Mild spill (~8 regs) is fire-and-forget scratch traffic — cheaper than losing occupancy.
// W4 quads (vs 28 strided scalar weight loads) shorten Stage-A's VMEM issue/latency chain.
__global__ __launch_bounds__(256, 4) void k_conv(
    const unsigned short* __restrict__ xT,
    const uint4* __restrict__ W4,
    const unsigned short* __restrict__ cW,
    const float* __restrict__ bias,
    unsigned short* __restrict__ pre,
    float* __restrict__ stats)
{
    // F: 64 rows x 256 bf16 (512 B/row), XOR-swizzled in 16B groups (conflict-free)
    __shared__ unsigned short Fbuf[VT * 256];       // 32 KB; reused as float outT[64][68]
    __shared__ float sred[4][4][4];

    const int bid   = blockIdx.x;
    const int b     = bid & 7;                // b <-> XCD affinity: xT[b] slab L2-resident
    const int tile  = bid >> 3;
    const int vbase = tile * VT;
    const int tid   = threadIdx.x;
    const int wave  = tid >> 6;
    const int lane  = tid & 63;
    const int q     = lane >> 4;
    const int l15   = lane & 15;

    // ---- Stage A: thread (v=lane, ch-chunk = wave*16..+16); deep gather prefetch ----
    // Weights via W4: one aligned uint4 {idx,L,E,N} per (v,k) -> 7 dwordx4 loads.
    {
        const int v  = lane;
        const int ic = wave;
        const int vg = vbase + v;

        uint4 wq[KK];
        if (vg < NVV) {
            const uint4* wp = W4 + (size_t)vg * KK;
            #pragma unroll
            for (int k = 0; k < KK; ++k) wq[k] = wp[k];
        } else {
            #pragma unroll
            for (int k = 0; k < KK; ++k) wq[k] = make_uint4(NVP, 0u, 0u, 0u);
        }
        const unsigned short* xTb = xT + (size_t)b * NVP * 64 + ic * 16;

        uint4 ga[KK], gb[KK], gu0, gu1;
        gu0 = gu1 = make_uint4(0, 0, 0, 0);
        #pragma unroll
        for (int k = 0; k < KK; ++k) { ga[k] = make_uint4(0,0,0,0); gb[k] = make_uint4(0,0,0,0); }
        if (vg < NVP) {
            const uint4* p = (const uint4*)(xTb + (size_t)vg * 64);
            gu0 = p[0]; gu1 = p[1];
        }
        #pragma unroll
        for (int k = 0; k < KK; ++k) {          // all 7 gathers issued before any use
            const int j = (int)wq[k].x;
            if (j < NVP) {
                const uint4* p = (const uint4*)(xTb + (size_t)j * 64);
                ga[k] = p[0]; gb[k] = p[1];
            }
        }

        float l[16], e[16], n[16];
        #pragma unroll
        for (int t = 0; t < 16; ++t) { l[t] = e[t] = n[t] = 0.f; }
        #pragma unroll
        for (int k = 0; k < KK; ++k) {
            const float a   = __builtin_bit_cast(float, wq[k].y);
            const float bb2 = __builtin_bit_cast(float, wq[k].z);
            const float c2  = __builtin_bit_cast(float, wq[k].w);
            const unsigned uu[8] = { ga[k].x, ga[k].y, ga[k].z, ga[k].w,
                                     gb[k].x, gb[k].y, gb[k].z, gb[k].w };
            #pragma unroll
            for (int j2 = 0; j2 < 8; ++j2) {
                float f0 = bflo(uu[j2]), f1 = bfhi(uu[j2]);   // zeros contribute 0
                l[2*j2]   = fmaf(f0, a,  l[2*j2]);   e[2*j2]   = fmaf(f0, bb2, e[2*j2]);   n[2*j2]   = fmaf(f0, c2, n[2*j2]);
                l[2*j2+1] = fmaf(f1, a,  l[2*j2+1]); e[2*j2+1] = fmaf(f1, bb2, e[2*j2+1]); n[2*j2+1] = fmaf(f1, c2, n[2*j2+1]);
            }
        }
        // pack into F: group g holds k=8g..8g+7 = ch-pair {2g,2g+1} x {u,l,e,n}
        const unsigned uup[8] = { gu0.x, gu0.y, gu0.z, gu0.w, gu1.x, gu1.y, gu1.z, gu1.w };
        #pragma unroll
        for (int jg = 0; jg < 8; ++jg) {
            const int i0 = 2 * jg;
            uint4 w;
            w.x = pk2(bflo(uup[jg]), l[i0]);        // u bf16 passthrough is exact
            w.y = pk2(e[i0],   n[i0]);
            w.z = pk2(bfhi(uup[jg]) , l[i0+1]);
            w.w = pk2(e[i0+1], n[i0+1]);
            const int g    = ic * 8 + jg;
            const int phys = g ^ (v & 31);
            *(uint4*)(Fbuf + v * 256 + phys * 8) = w;
        }
    }
    __syncthreads();

    // ---- W fragments (A-operand): lane holds A[m=l15][k=32*k0+8*q+j]; direct bf16 load ----
    short8 afrag[8];
    {
        const unsigned short* wrow = cW + (16 * wave + l15) * KDIM + q * 8;
        #pragma unroll
        for (int k0 = 0; k0 < 8; ++k0)
            afrag[k0] = *(const short8*)(wrow + k0 * 32);
    }

    // ---- MFMA: B[n=l15][k] from swizzled F ----
    floatx4 acc[4] = {{0,0,0,0},{0,0,0,0},{0,0,0,0},{0,0,0,0}};
    #pragma unroll
    for (int k0 = 0; k0 < 8; ++k0) {
        #pragma unroll
        for (int nt = 0; nt < 4; ++nt) {
            const int row  = nt * 16 + l15;
            const int phys = (k0 * 4 + q) ^ (row & 31);
            const short8 bfrag = *(const short8*)(Fbuf + row * 256 + phys * 8);
            acc[nt] = __builtin_amdgcn_mfma_f32_16x16x32_bf16(afrag[k0], bfrag, acc[nt], 0, 0, 0);
        }
    }

    // ---- Epilogue: bias, GN partial stats, bf16 pre-GN stores via LDS transpose ----
    float bs[4];
    #pragma unroll
    for (int r = 0; r < 4; ++r) bs[r] = bias[16 * wave + q * 4 + r];

    float cv[4][4];
    float sA = 0.f, s2A = 0.f, sB = 0.f, s2B = 0.f;
    #pragma unroll
    for (int nt = 0; nt < 4; ++nt) {
        const bool ok = (vbase + nt * 16 + l15 < NVV);
        #pragma unroll
        for (int r = 0; r < 4; ++r) {
            float cc = acc[nt][r] + bs[r];
            cv[nt][r] = cc;
            if (ok) {
                if (r < 2) { sA += cc; s2A = fmaf(cc, cc, s2A); }
                else       { sB += cc; s2B = fmaf(cc, cc, s2B); }
            }
        }
    }
    #pragma unroll
    for (int m = 1; m < 16; m <<= 1) {
        sA  += __shfl_xor(sA,  m);
        s2A += __shfl_xor(s2A, m);
        sB  += __shfl_xor(sB,  m);
        s2B += __shfl_xor(s2B, m);
    }
    if (l15 == 0) {
        sred[wave][q][0] = sA; sred[wave][q][1] = s2A;
        sred[wave][q][2] = sB; sred[wave][q][3] = s2B;
    }
    __syncthreads();                 // F reads done; reuse Fbuf as outT

    float* outT = (float*)Fbuf;      // [64 o][stride 68]
    #pragma unroll
    for (int nt = 0; nt < 4; ++nt)
        #pragma unroll
        for (int r = 0; r < 4; ++r)
            outT[(16 * wave + 4 * q + r) * 68 + nt * 16 + l15] = cv[nt][r];
    __syncthreads();

    {   // all 64 lanes: (oo-half = lane>>5, vpair = lane&31); 2 rows x 128 B per iter
        const int oo2  = lane >> 5;
        const int vloc = 2 * (lane & 31);
        if (vbase + vloc < NVV) {    // pair {v,v+1}: both valid or both OOB (NVV even)
            unsigned short* prow = pre + (size_t)(b * COUT + 16 * wave) * PSTRIDE + vbase;
            #pragma unroll
            for (int ot = 0; ot < 8; ++ot) {
                const int oo = 2 * ot + oo2;
                float2 t = *(const float2*)(outT + (16 * wave + oo) * 68 + vloc);
                *(unsigned*)(prow + (size_t)oo * PSTRIDE + vloc) = pk2(t.x, t.y);
            }
        }
    }

    if (tid < 64) {
        const int w = tid >> 4, qq = (tid >> 2) & 3, e = tid & 3;
        const int g = 8 * w + 2 * qq + (e >> 1);
        atomicAdd(&stats[b * 64 + 2 * g + (e & 1)], sred[w][qq][e]);
    }
}

// grid: 2048 blocks; blk = b + 8*(o + 64*quarter) -> blk%8==b matches k_conv's
// writer XCD (pre[b] rows live in XCD b's L2). Split-stream: read bf16 pre, write f32 out.
__global__ __launch_bounds__(256) void k_norm(
    const unsigned short* __restrict__ pre,
    float* __restrict__ out,
    const float* __restrict__ stats,
    const float* __restrict__ gamma,
    const float* __restrict__ beta)
{
    const int blk     = blockIdx.x;
    const int b       = blk & 7;
    const int rest    = blk >> 3;               // 0..255
    const int o       = rest & 63;
    const int quarter = rest >> 6;
    const int row     = b * 64 + o;
    const int g = o >> 1;
    const float inv_cnt = 1.f / (float)(2 * NVV);
    const float mean = stats[b * 64 + 2 * g] * inv_cnt;
    const float var  = fmaf(stats[b * 64 + 2 * g + 1], inv_cnt, -mean * mean);
    const float rs   = rsqrtf(var + EPSV);
    const float sc   = gamma[o] * rs;
    const float sh   = fmaf(-mean, sc, beta[o]);

    const uint4* src = (const uint4*)(pre + (size_t)row * PSTRIDE);
    float* orow = out + (size_t)row * NVV;
    #pragma unroll
    for (int it = 0; it < 5; ++it) {            // 4 quarters x 5 x 256 = 5120 uint4 = v<40960
        const int c = quarter * 1280 + it * 256 + (int)threadIdx.x;
        uint4 u = src[c];
        float f[8] = { bflo(u.x), bfhi(u.x), bflo(u.y), bfhi(u.y),
                       bflo(u.z), bfhi(u.z), bflo(u.w), bfhi(u.w) };
        float* p = orow + 8 * c;
        #pragma unroll
        for (int t = 0; t < 4; ++t) {
            float y0 = fmaf(f[2*t],   sc, sh);
            float y1 = fmaf(f[2*t+1], sc, sh);
            float2 v2 = make_float2(y0 > 0.f ? y0 : 0.f, y1 > 0.f ? y1 : 0.f);
            *(float2*)(p + 2 * t) = v2;         // 8B-aligned always
        }
    }
    if (quarter == 3 && threadIdx.x == 0) {     // tail v = 40960, 40961
        unsigned u = *(const unsigned*)(pre + (size_t)row * PSTRIDE + 40960);
        float y0 = fmaf(bflo(u), sc, sh);
        float y1 = fmaf(bfhi(u), sc, sh);
        *(float2*)(orow + 40960) = make_float2(y0 > 0.f ? y0 : 0.f, y1 > 0.f ? y1 : 0.f);
    }
}

extern "C" void kernel_launch(void* const* d_in, const int* in_sizes, int n_in,
                              void* d_out, int out_size, void* d_ws, size_t ws_size,
                              hipStream_t stream) {
    const float* x      = (const float*)d_in[0];
    const float* Lw     = (const float*)d_in[1];
    const float* Ew     = (const float*)d_in[2];
    const float* Nw     = (const float*)d_in[3];
    const float* coeffs = (const float*)d_in[4];
    const float* bias   = (const float*)d_in[5];
    const float* gamma  = (const float*)d_in[6];
    const float* beta   = (const float*)d_in[7];
    const int*   nbr    = (const int*)d_in[8];
    float* out = (float*)d_out;
    float*          stats = (float*)d_ws;
    unsigned short* cW    = (unsigned short*)((char*)d_ws + CW_OFF);
    unsigned short* xT    = (unsigned short*)((char*)d_ws + XT_OFF);
    unsigned short* pre   = (unsigned short*)((char*)d_ws + PRE_OFF);
    uint4*          W4    = (uint4*)((char*)d_ws + W4_OFF);            // needs ws >= ~57.2 MB

    k_tr<<<dim3(161, BB), dim3(256), 0, stream>>>(x, xT, coeffs, cW, stats, Lw, Ew, Nw, nbr, W4);

    k_conv<<<dim3(BB * NTILE), dim3(256), 0, stream>>>(xT, W4, cW, bias, pre, stats);

    k_norm<<<dim3(4 * BB * COUT), dim3(256), 0, stream>>>(pre, out, stats, gamma, beta);
}

// Round 7
// 204.803 us; speedup vs baseline: 1.1005x; 1.0044x over previous
//
#include <hip/hip_runtime.h>
#include <hip/hip_bf16.h>

#define NVV    40962
#define NVP    10242
#define BB     8
#define CIN    64
#define COUT   64
#define KK     7
#define EPSV   1e-5f

#define VT      64           // vertices per tile
#define NTILE   641          // ceil(NVV/VT)
#define KDIM    256          // Cin*4
#define PSTRIDE 41024        // padded pre-GN row (bf16): 82048 B = 641 x 128 B  (line-aligned!)

// d_ws layout (total ~57.2 MB):
#define CW_OFF  2048         // cW bf16 coeffs [64][256]
#define XT_OFF  36864        // xT bf16 [b][v][i] : 8*10242*64*2 = 10,487,808 B
#define PRE_OFF 10524672     // pre bf16 [row][PSTRIDE] : 512*41024*2 = 42,008,576 B (128B-aligned)
#define W4_OFF  52533248     // uint4 [NVV*KK] {idx,L,E,N} : 40962*7*16 = 4,587,744 B

typedef __attribute__((ext_vector_type(8))) short short8;
typedef __attribute__((ext_vector_type(4))) float floatx4;

__device__ __forceinline__ unsigned f2bf(float f) {
    unsigned u = __builtin_bit_cast(unsigned, f);
    return (u + 0x7FFFu + ((u >> 16) & 1u)) >> 16;    // rne (finite inputs)
}
__device__ __forceinline__ unsigned pk2(float a, float b) {   // v_cvt_pk_bf16_f32
    __hip_bfloat162 h = __float22bfloat162_rn(make_float2(a, b));
    unsigned r;
    __builtin_memcpy(&r, &h, 4);
    return r;
}
__device__ __forceinline__ float bflo(unsigned u) { return __builtin_bit_cast(float, u << 16); }
__device__ __forceinline__ float bfhi(unsigned u) { return __builtin_bit_cast(float, u & 0xffff0000u); }

// ---- transpose x -> bf16 xT[b][v][i]; zip weight quads W4; block (0,0) zeroes stats + coeffs ----
__global__ __launch_bounds__(256) void k_tr(const float* __restrict__ x,
                                            unsigned short* __restrict__ xT,
                                            const float* __restrict__ coeffs,
                                            unsigned short* __restrict__ cW,
                                            float* __restrict__ stats,
                                            const float* __restrict__ Lw,
                                            const float* __restrict__ Ew,
                                            const float* __restrict__ Nw,
                                            const int*   __restrict__ nbr,
                                            uint4* __restrict__ W4) {
    __shared__ float tile[64][65];
    const int b    = blockIdx.y;
    const int v0   = blockIdx.x * 64;
    const int lane = threadIdx.x & 63;
    const int wave = threadIdx.x >> 6;
    const int v    = v0 + lane;

    // zip {idx,L,E,N} -> one aligned 16B quad per (v,k); linear index IS v*7+k
    {
        const int gid = (blockIdx.y * 161 + blockIdx.x) * 256 + (int)threadIdx.x;
        if (gid < NVV * KK) {
            uint4 qd;
            qd.x = (unsigned)nbr[gid];
            qd.y = __builtin_bit_cast(unsigned, Lw[gid]);
            qd.z = __builtin_bit_cast(unsigned, Ew[gid]);
            qd.w = __builtin_bit_cast(unsigned, Nw[gid]);
            W4[gid] = qd;
        }
    }

    #pragma unroll
    for (int r = 0; r < 16; ++r) {
        int i = wave * 16 + r;
        tile[i][lane] = (v < NVP) ? x[((size_t)b * CIN + i) * NVP + v] : 0.f;
    }
    if (blockIdx.x == 0 && b == 0) {
        for (int t = threadIdx.x; t < 512; t += 256) stats[t] = 0.f;
        for (int t = threadIdx.x; t < COUT * KDIM; t += 256)
            cW[t] = (unsigned short)f2bf(coeffs[t]);
    }
    __syncthreads();
    const int i2 = lane & 31;
    #pragma unroll
    for (int r = 0; r < 8; ++r) {
        int vv = wave * 16 + 2 * r + (lane >> 5);
        if (v0 + vv < NVP) {
            unsigned w = pk2(tile[2 * i2][vv], tile[2 * i2 + 1][vv]);
            ((unsigned*)(xT + ((size_t)b * NVP + v0 + vv) * 64))[i2] = w;
        }
    }
}

// (256,4): empirically fastest (r0/r4/r5/r6): 64-VGPR cap + 4 blocks/CU; mild spill is
// fire-and-forget. Stage-A lane remap (v = wave*16+l15, ic = q): each wave's gathers
// cover 16 rows x full 128B width -> 32 cache lines/instr instead of 64 (2x TA cut);
// W4 quad loads 4-way lane-shared (-> ~16 lines/instr, was 64). Swizzle gains ^(g>>3)
// so bank spread is preserved with ic varying inside a wave (map stays bijective).
__global__ __launch_bounds__(256, 4) void k_conv(
    const unsigned short* __restrict__ xT,
    const uint4* __restrict__ W4,
    const unsigned short* __restrict__ cW,
    const float* __restrict__ bias,
    unsigned short* __restrict__ pre,
    float* __restrict__ stats)
{
    // F: 64 rows x 256 bf16 (512 B/row), XOR-swizzled in 16B groups
    __shared__ unsigned short Fbuf[VT * 256];       // 32 KB; reused as float outT[64][68]
    __shared__ float sred[4][4][4];

    const int bid   = blockIdx.x;
    const int b     = bid & 7;                // b <-> XCD affinity: xT[b] slab L2-resident
    const int tile  = bid >> 3;
    const int vbase = tile * VT;
    const int tid   = threadIdx.x;
    const int wave  = tid >> 6;
    const int lane  = tid & 63;
    const int q     = lane >> 4;
    const int l15   = lane & 15;

    // ---- Stage A: thread (v = wave*16+l15, ch-chunk ic = q); deep gather prefetch ----
    {
        const int v  = wave * 16 + l15;       // 16 consecutive rows per wave
        const int ic = q;                     // 4 lanes tile one row's 128 B
        const int vg = vbase + v;

        uint4 wq[KK];
        if (vg < NVV) {
            const uint4* wp = W4 + (size_t)vg * KK;
            #pragma unroll
            for (int k = 0; k < KK; ++k) wq[k] = wp[k];
        } else {
            #pragma unroll
            for (int k = 0; k < KK; ++k) wq[k] = make_uint4(NVP, 0u, 0u, 0u);
        }
        const unsigned short* xTb = xT + (size_t)b * NVP * 64 + ic * 16;

        uint4 ga[KK], gb[KK], gu0, gu1;
        gu0 = gu1 = make_uint4(0, 0, 0, 0);
        #pragma unroll
        for (int k = 0; k < KK; ++k) { ga[k] = make_uint4(0,0,0,0); gb[k] = make_uint4(0,0,0,0); }
        if (vg < NVP) {
            const uint4* p = (const uint4*)(xTb + (size_t)vg * 64);
            gu0 = p[0]; gu1 = p[1];
        }
        #pragma unroll
        for (int k = 0; k < KK; ++k) {          // all 7 gathers issued before any use
            const int j = (int)wq[k].x;
            if (j < NVP) {
                const uint4* p = (const uint4*)(xTb + (size_t)j * 64);
                ga[k] = p[0]; gb[k] = p[1];
            }
        }

        float l[16], e[16], n[16];
        #pragma unroll
        for (int t = 0; t < 16; ++t) { l[t] = e[t] = n[t] = 0.f; }
        #pragma unroll
        for (int k = 0; k < KK; ++k) {
            const float a   = __builtin_bit_cast(float, wq[k].y);
            const float bb2 = __builtin_bit_cast(float, wq[k].z);
            const float c2  = __builtin_bit_cast(float, wq[k].w);
            const unsigned uu[8] = { ga[k].x, ga[k].y, ga[k].z, ga[k].w,
                                     gb[k].x, gb[k].y, gb[k].z, gb[k].w };
            #pragma unroll
            for (int j2 = 0; j2 < 8; ++j2) {
                float f0 = bflo(uu[j2]), f1 = bfhi(uu[j2]);   // zeros contribute 0
                l[2*j2]   = fmaf(f0, a,  l[2*j2]);   e[2*j2]   = fmaf(f0, bb2, e[2*j2]);   n[2*j2]   = fmaf(f0, c2, n[2*j2]);
                l[2*j2+1] = fmaf(f1, a,  l[2*j2+1]); e[2*j2+1] = fmaf(f1, bb2, e[2*j2+1]); n[2*j2+1] = fmaf(f1, c2, n[2*j2+1]);
            }
        }
        // pack into F: group g holds k=8g..8g+7 = ch-pair {2g,2g+1} x {u,l,e,n}
        const unsigned uup[8] = { gu0.x, gu0.y, gu0.z, gu0.w, gu1.x, gu1.y, gu1.z, gu1.w };
        #pragma unroll
        for (int jg = 0; jg < 8; ++jg) {
            const int i0 = 2 * jg;
            uint4 w;
            w.x = pk2(bflo(uup[jg]), l[i0]);        // u bf16 passthrough is exact
            w.y = pk2(e[i0],   n[i0]);
            w.z = pk2(bfhi(uup[jg]) , l[i0+1]);
            w.w = pk2(e[i0+1], n[i0+1]);
            const int g    = ic * 8 + jg;
            const int phys = g ^ (v & 31) ^ (g >> 3);   // bijective; ic spread into banks
            *(uint4*)(Fbuf + v * 256 + phys * 8) = w;
        }
    }
    __syncthreads();

    // ---- W fragments (A-operand): lane holds A[m=l15][k=32*k0+8*q+j]; direct bf16 load ----
    short8 afrag[8];
    {
        const unsigned short* wrow = cW + (16 * wave + l15) * KDIM + q * 8;
        #pragma unroll
        for (int k0 = 0; k0 < 8; ++k0)
            afrag[k0] = *(const short8*)(wrow + k0 * 32);
    }

    // ---- MFMA: B[n=l15][k] from swizzled F (same phys map as writer) ----
    floatx4 acc[4] = {{0,0,0,0},{0,0,0,0},{0,0,0,0},{0,0,0,0}};
    #pragma unroll
    for (int k0 = 0; k0 < 8; ++k0) {
        #pragma unroll
        for (int nt = 0; nt < 4; ++nt) {
            const int row  = nt * 16 + l15;
            const int kg   = k0 * 4 + q;
            const int phys = kg ^ (row & 31) ^ (kg >> 3);
            const short8 bfrag = *(const short8*)(Fbuf + row * 256 + phys * 8);
            acc[nt] = __builtin_amdgcn_mfma_f32_16x16x32_bf16(afrag[k0], bfrag, acc[nt], 0, 0, 0);
        }
    }

    // ---- Epilogue: bias, GN partial stats, bf16 pre-GN stores via LDS transpose ----
    float bs[4];
    #pragma unroll
    for (int r = 0; r < 4; ++r) bs[r] = bias[16 * wave + q * 4 + r];

    float cv[4][4];
    float sA = 0.f, s2A = 0.f, sB = 0.f, s2B = 0.f;
    #pragma unroll
    for (int nt = 0; nt < 4; ++nt) {
        const bool ok = (vbase + nt * 16 + l15 < NVV);
        #pragma unroll
        for (int r = 0; r < 4; ++r) {
            float cc = acc[nt][r] + bs[r];
            cv[nt][r] = cc;
            if (ok) {
                if (r < 2) { sA += cc; s2A = fmaf(cc, cc, s2A); }
                else       { sB += cc; s2B = fmaf(cc, cc, s2B); }
            }
        }
    }
    #pragma unroll
    for (int m = 1; m < 16; m <<= 1) {
        sA  += __shfl_xor(sA,  m);
        s2A += __shfl_xor(s2A, m);
        sB  += __shfl_xor(sB,  m);
        s2B += __shfl_xor(s2B, m);
    }
    if (l15 == 0) {
        sred[wave][q][0] = sA; sred[wave][q][1] = s2A;
        sred[wave][q][2] = sB; sred[wave][q][3] = s2B;
    }
    __syncthreads();                 // F reads done; reuse Fbuf as outT

    float* outT = (float*)Fbuf;      // [64 o][stride 68]
    #pragma unroll
    for (int nt = 0; nt < 4; ++nt)
        #pragma unroll
        for (int r = 0; r < 4; ++r)
            outT[(16 * wave + 4 * q + r) * 68 + nt * 16 + l15] = cv[nt][r];
    __syncthreads();

    {   // all 64 lanes: (oo-half = lane>>5, vpair = lane&31); 2 rows x 128 B per iter
        const int oo2  = lane >> 5;
        const int vloc = 2 * (lane & 31);
        if (vbase + vloc < NVV) {    // pair {v,v+1}: both valid or both OOB (NVV even)
            unsigned short* prow = pre + (size_t)(b * COUT + 16 * wave) * PSTRIDE + vbase;
            #pragma unroll
            for (int ot = 0; ot < 8; ++ot) {
                const int oo = 2 * ot + oo2;
                float2 t = *(const float2*)(outT + (16 * wave + oo) * 68 + vloc);
                *(unsigned*)(prow + (size_t)oo * PSTRIDE + vloc) = pk2(t.x, t.y);
            }
        }
    }

    if (tid < 64) {
        const int w = tid >> 4, qq = (tid >> 2) & 3, e = tid & 3;
        const int g = 8 * w + 2 * qq + (e >> 1);
        atomicAdd(&stats[b * 64 + 2 * g + (e & 1)], sred[w][qq][e]);
    }
}

// grid: 2048 blocks; blk = b + 8*(o + 64*quarter) -> blk%8==b matches k_conv's
// writer XCD (pre[b] rows live in XCD b's L2). Split-stream: read bf16 pre, write f32 out.
__global__ __launch_bounds__(256) void k_norm(
    const unsigned short* __restrict__ pre,
    float* __restrict__ out,
    const float* __restrict__ stats,
    const float* __restrict__ gamma,
    const float* __restrict__ beta)
{
    const int blk     = blockIdx.x;
    const int b       = blk & 7;
    const int rest    = blk >> 3;               // 0..255
    const int o       = rest & 63;
    const int quarter = rest >> 6;
    const int row     = b * 64 + o;
    const int g = o >> 1;
    const float inv_cnt = 1.f / (float)(2 * NVV);
    const float mean = stats[b * 64 + 2 * g] * inv_cnt;
    const float var  = fmaf(stats[b * 64 + 2 * g + 1], inv_cnt, -mean * mean);
    const float rs   = rsqrtf(var + EPSV);
    const float sc   = gamma[o] * rs;
    const float sh   = fmaf(-mean, sc, beta[o]);

    const uint4* src = (const uint4*)(pre + (size_t)row * PSTRIDE);
    float* orow = out + (size_t)row * NVV;
    #pragma unroll
    for (int it = 0; it < 5; ++it) {            // 4 quarters x 5 x 256 = 5120 uint4 = v<40960
        const int c = quarter * 1280 + it * 256 + (int)threadIdx.x;
        uint4 u = src[c];
        float f[8] = { bflo(u.x), bfhi(u.x), bflo(u.y), bfhi(u.y),
                       bflo(u.z), bfhi(u.z), bflo(u.w), bfhi(u.w) };
        float* p = orow + 8 * c;                // 32B-aligned
        float4 o0, o1;
        float y;
        y = fmaf(f[0], sc, sh); o0.x = y > 0.f ? y : 0.f;
        y = fmaf(f[1], sc, sh); o0.y = y > 0.f ? y : 0.f;
        y = fmaf(f[2], sc, sh); o0.z = y > 0.f ? y : 0.f;
        y = fmaf(f[3], sc, sh); o0.w = y > 0.f ? y : 0.f;
        y = fmaf(f[4], sc, sh); o1.x = y > 0.f ? y : 0.f;
        y = fmaf(f[5], sc, sh); o1.y = y > 0.f ? y : 0.f;
        y = fmaf(f[6], sc, sh); o1.z = y > 0.f ? y : 0.f;
        y = fmaf(f[7], sc, sh); o1.w = y > 0.f ? y : 0.f;
        *(float4*)(p)     = o0;                 // 2 x dwordx4 stores
        *(float4*)(p + 4) = o1;
    }
    if (quarter == 3 && threadIdx.x == 0) {     // tail v = 40960, 40961
        unsigned u = *(const unsigned*)(pre + (size_t)row * PSTRIDE + 40960);
        float y0 = fmaf(bflo(u), sc, sh);
        float y1 = fmaf(bfhi(u), sc, sh);
        *(float2*)(orow + 40960) = make_float2(y0 > 0.f ? y0 : 0.f, y1 > 0.f ? y1 : 0.f);
    }
}

extern "C" void kernel_launch(void* const* d_in, const int* in_sizes, int n_in,
                              void* d_out, int out_size, void* d_ws, size_t ws_size,
                              hipStream_t stream) {
    const float* x      = (const float*)d_in[0];
    const float* Lw     = (const float*)d_in[1];
    const float* Ew     = (const float*)d_in[2];
    const float* Nw     = (const float*)d_in[3];
    const float* coeffs = (const float*)d_in[4];
    const float* bias   = (const float*)d_in[5];
    const float* gamma  = (const float*)d_in[6];
    const float* beta   = (const float*)d_in[7];
    const int*   nbr    = (const int*)d_in[8];
    float* out = (float*)d_out;
    float*          stats = (float*)d_ws;
    unsigned short* cW    = (unsigned short*)((char*)d_ws + CW_OFF);
    unsigned short* xT    = (unsigned short*)((char*)d_ws + XT_OFF);
    unsigned short* pre   = (unsigned short*)((char*)d_ws + PRE_OFF);
    uint4*          W4    = (uint4*)((char*)d_ws + W4_OFF);            // needs ws >= ~57.2 MB

    k_tr<<<dim3(161, BB), dim3(256), 0, stream>>>(x, xT, coeffs, cW, stats, Lw, Ew, Nw, nbr, W4);

    k_conv<<<dim3(BB * NTILE), dim3(256), 0, stream>>>(xT, W4, cW, bias, pre, stats);

    k_norm<<<dim3(4 * BB * COUT), dim3(256), 0, stream>>>(pre, out, stats, gamma, beta);
}

// Round 8
// 186.839 us; speedup vs baseline: 1.2063x; 1.0962x over previous
//
#include <hip/hip_runtime.h>
#include <hip/hip_bf16.h>

#define NVV    40962
#define NVP    10242
#define BB     8
#define CIN    64
#define COUT   64
#define KK     7
#define EPSV   1e-5f

#define VT      64           // vertices per tile
#define NTILE   641          // ceil(NVV/VT)
#define KDIM    256          // Cin*4
#define PSTRIDE 41024        // padded pre-GN row (bf16): 82048 B = 641 x 128 B  (line-aligned!)

// d_ws layout (total ~57.2 MB):
#define CW_OFF  2048         // cW bf16 coeffs [64][256]
#define XT_OFF  36864        // xT bf16 [b][v][i] : 8*10242*64*2 = 10,487,808 B
#define PRE_OFF 10524672     // pre bf16 [row][PSTRIDE] : 512*41024*2 = 42,008,576 B (128B-aligned)
#define W4_OFF  52533248     // uint4 [NVV*KK] {idx,L,E,N} : 40962*7*16 = 4,587,744 B

typedef __attribute__((ext_vector_type(8))) short short8;
typedef __attribute__((ext_vector_type(4))) float floatx4;

__device__ __forceinline__ unsigned f2bf(float f) {
    unsigned u = __builtin_bit_cast(unsigned, f);
    return (u + 0x7FFFu + ((u >> 16) & 1u)) >> 16;    // rne (finite inputs)
}
__device__ __forceinline__ unsigned pk2(float a, float b) {   // v_cvt_pk_bf16_f32
    __hip_bfloat162 h = __float22bfloat162_rn(make_float2(a, b));
    unsigned r;
    __builtin_memcpy(&r, &h, 4);
    return r;
}
__device__ __forceinline__ float bflo(unsigned u) { return __builtin_bit_cast(float, u << 16); }
__device__ __forceinline__ float bfhi(unsigned u) { return __builtin_bit_cast(float, u & 0xffff0000u); }

// ---- transpose x -> bf16 xT[b][v][i]; zip weight quads W4; block (0,0) zeroes stats + coeffs ----
__global__ __launch_bounds__(256) void k_tr(const float* __restrict__ x,
                                            unsigned short* __restrict__ xT,
                                            const float* __restrict__ coeffs,
                                            unsigned short* __restrict__ cW,
                                            float* __restrict__ stats,
                                            const float* __restrict__ Lw,
                                            const float* __restrict__ Ew,
                                            const float* __restrict__ Nw,
                                            const int*   __restrict__ nbr,
                                            uint4* __restrict__ W4) {
    __shared__ float tile[64][65];
    const int b    = blockIdx.y;
    const int v0   = blockIdx.x * 64;
    const int lane = threadIdx.x & 63;
    const int wave = threadIdx.x >> 6;
    const int v    = v0 + lane;

    // zip {idx,L,E,N} -> one aligned 16B quad per (v,k); linear index IS v*7+k
    {
        const int gid = (blockIdx.y * 161 + blockIdx.x) * 256 + (int)threadIdx.x;
        if (gid < NVV * KK) {
            uint4 qd;
            qd.x = (unsigned)nbr[gid];
            qd.y = __builtin_bit_cast(unsigned, Lw[gid]);
            qd.z = __builtin_bit_cast(unsigned, Ew[gid]);
            qd.w = __builtin_bit_cast(unsigned, Nw[gid]);
            W4[gid] = qd;
        }
    }

    #pragma unroll
    for (int r = 0; r < 16; ++r) {
        int i = wave * 16 + r;
        tile[i][lane] = (v < NVP) ? x[((size_t)b * CIN + i) * NVP + v] : 0.f;
    }
    if (blockIdx.x == 0 && b == 0) {
        for (int t = threadIdx.x; t < 512; t += 256) stats[t] = 0.f;
        for (int t = threadIdx.x; t < COUT * KDIM; t += 256)
            cW[t] = (unsigned short)f2bf(coeffs[t]);
    }
    __syncthreads();
    const int i2 = lane & 31;
    #pragma unroll
    for (int r = 0; r < 8; ++r) {
        int vv = wave * 16 + 2 * r + (lane >> 5);
        if (v0 + vv < NVP) {
            unsigned w = pk2(tile[2 * i2][vv], tile[2 * i2 + 1][vv]);
            ((unsigned*)(xT + ((size_t)b * NVP + v0 + vv) * 64))[i2] = w;
        }
    }
}

// r6 winner (v=lane, ic=wave, W4, (256,4)) + LDS shrunk to EXACTLY 32768 B via sred
// aliasing Fbuf's dead tail -> 5 blocks/CU (5*32768 = 160 KiB exact), was 4 at 33280.
// (256,4) keeps the proven 64-VGPR point (mild fire-and-forget spill beats lost waves).
__global__ __launch_bounds__(256, 4) void k_conv(
    const unsigned short* __restrict__ xT,
    const uint4* __restrict__ W4,
    const unsigned short* __restrict__ cW,
    const float* __restrict__ bias,
    unsigned short* __restrict__ pre,
    float* __restrict__ stats)
{
    // F: 64 rows x 256 bf16 (512 B/row), XOR-swizzled in 16B groups (conflict-free)
    __shared__ unsigned short Fbuf[VT * 256];       // 32768 B total; reused as outT + sred
    float* const sredA = (float*)(Fbuf + 14336);    // byte 28672; disjoint from outT (<=17408)

    const int bid   = blockIdx.x;
    const int b     = bid & 7;                // b <-> XCD affinity: xT[b] slab L2-resident
    const int tile  = bid >> 3;
    const int vbase = tile * VT;
    const int tid   = threadIdx.x;
    const int wave  = tid >> 6;
    const int lane  = tid & 63;
    const int q     = lane >> 4;
    const int l15   = lane & 15;

    // ---- Stage A: thread (v=lane, ch-chunk = wave*16..+16); deep gather prefetch ----
    // Weights via W4: one aligned uint4 {idx,L,E,N} per (v,k) -> 7 dwordx4 loads.
    {
        const int v  = lane;
        const int ic = wave;                  // wave-uniform -> SGPR base addressing
        const int vg = vbase + v;

        uint4 wq[KK];
        if (vg < NVV) {
            const uint4* wp = W4 + (size_t)vg * KK;
            #pragma unroll
            for (int k = 0; k < KK; ++k) wq[k] = wp[k];
        } else {
            #pragma unroll
            for (int k = 0; k < KK; ++k) wq[k] = make_uint4(NVP, 0u, 0u, 0u);
        }
        const unsigned short* xTb = xT + (size_t)b * NVP * 64 + ic * 16;

        uint4 ga[KK], gb[KK], gu0, gu1;
        gu0 = gu1 = make_uint4(0, 0, 0, 0);
        #pragma unroll
        for (int k = 0; k < KK; ++k) { ga[k] = make_uint4(0,0,0,0); gb[k] = make_uint4(0,0,0,0); }
        if (vg < NVP) {
            const uint4* p = (const uint4*)(xTb + (size_t)vg * 64);
            gu0 = p[0]; gu1 = p[1];
        }
        #pragma unroll
        for (int k = 0; k < KK; ++k) {          // all 7 gathers issued before any use
            const int j = (int)wq[k].x;
            if (j < NVP) {
                const uint4* p = (const uint4*)(xTb + (size_t)j * 64);
                ga[k] = p[0]; gb[k] = p[1];
            }
        }

        float l[16], e[16], n[16];
        #pragma unroll
        for (int t = 0; t < 16; ++t) { l[t] = e[t] = n[t] = 0.f; }
        #pragma unroll
        for (int k = 0; k < KK; ++k) {
            const float a   = __builtin_bit_cast(float, wq[k].y);
            const float bb2 = __builtin_bit_cast(float, wq[k].z);
            const float c2  = __builtin_bit_cast(float, wq[k].w);
            const unsigned uu[8] = { ga[k].x, ga[k].y, ga[k].z, ga[k].w,
                                     gb[k].x, gb[k].y, gb[k].z, gb[k].w };
            #pragma unroll
            for (int j2 = 0; j2 < 8; ++j2) {
                float f0 = bflo(uu[j2]), f1 = bfhi(uu[j2]);   // zeros contribute 0
                l[2*j2]   = fmaf(f0, a,  l[2*j2]);   e[2*j2]   = fmaf(f0, bb2, e[2*j2]);   n[2*j2]   = fmaf(f0, c2, n[2*j2]);
                l[2*j2+1] = fmaf(f1, a,  l[2*j2+1]); e[2*j2+1] = fmaf(f1, bb2, e[2*j2+1]); n[2*j2+1] = fmaf(f1, c2, n[2*j2+1]);
            }
        }
        // pack into F: group g holds k=8g..8g+7 = ch-pair {2g,2g+1} x {u,l,e,n}
        const unsigned uup[8] = { gu0.x, gu0.y, gu0.z, gu0.w, gu1.x, gu1.y, gu1.z, gu1.w };
        #pragma unroll
        for (int jg = 0; jg < 8; ++jg) {
            const int i0 = 2 * jg;
            uint4 w;
            w.x = pk2(bflo(uup[jg]), l[i0]);        // u bf16 passthrough is exact
            w.y = pk2(e[i0],   n[i0]);
            w.z = pk2(bfhi(uup[jg]) , l[i0+1]);
            w.w = pk2(e[i0+1], n[i0+1]);
            const int g    = ic * 8 + jg;
            const int phys = g ^ (v & 31);
            *(uint4*)(Fbuf + v * 256 + phys * 8) = w;
        }
    }
    __syncthreads();

    // ---- W fragments (A-operand): lane holds A[m=l15][k=32*k0+8*q+j]; direct bf16 load ----
    short8 afrag[8];
    {
        const unsigned short* wrow = cW + (16 * wave + l15) * KDIM + q * 8;
        #pragma unroll
        for (int k0 = 0; k0 < 8; ++k0)
            afrag[k0] = *(const short8*)(wrow + k0 * 32);
    }

    // ---- MFMA: B[n=l15][k] from swizzled F ----
    floatx4 acc[4] = {{0,0,0,0},{0,0,0,0},{0,0,0,0},{0,0,0,0}};
    #pragma unroll
    for (int k0 = 0; k0 < 8; ++k0) {
        #pragma unroll
        for (int nt = 0; nt < 4; ++nt) {
            const int row  = nt * 16 + l15;
            const int phys = (k0 * 4 + q) ^ (row & 31);
            const short8 bfrag = *(const short8*)(Fbuf + row * 256 + phys * 8);
            acc[nt] = __builtin_amdgcn_mfma_f32_16x16x32_bf16(afrag[k0], bfrag, acc[nt], 0, 0, 0);
        }
    }

    // ---- Epilogue: bias, GN partial stats, bf16 pre-GN stores via LDS transpose ----
    float bs[4];
    #pragma unroll
    for (int r = 0; r < 4; ++r) bs[r] = bias[16 * wave + q * 4 + r];

    float cv[4][4];
    float sA = 0.f, s2A = 0.f, sB = 0.f, s2B = 0.f;
    #pragma unroll
    for (int nt = 0; nt < 4; ++nt) {
        const bool ok = (vbase + nt * 16 + l15 < NVV);
        #pragma unroll
        for (int r = 0; r < 4; ++r) {
            float cc = acc[nt][r] + bs[r];
            cv[nt][r] = cc;
            if (ok) {
                if (r < 2) { sA += cc; s2A = fmaf(cc, cc, s2A); }
                else       { sB += cc; s2B = fmaf(cc, cc, s2B); }
            }
        }
    }
    #pragma unroll
    for (int m = 1; m < 16; m <<= 1) {
        sA  += __shfl_xor(sA,  m);
        s2A += __shfl_xor(s2A, m);
        sB  += __shfl_xor(sB,  m);
        s2B += __shfl_xor(s2B, m);
    }
    __syncthreads();                 // F reads done; Fbuf dead -> reuse as outT + sredA

    if (l15 == 0) {                  // safe: region disjoint from outT; read after next barrier
        float* sp = sredA + (wave * 4 + q) * 4;
        sp[0] = sA; sp[1] = s2A; sp[2] = sB; sp[3] = s2B;
    }

    float* outT = (float*)Fbuf;      // [64 o][stride 68] = 17408 B
    #pragma unroll
    for (int nt = 0; nt < 4; ++nt)
        #pragma unroll
        for (int r = 0; r < 4; ++r)
            outT[(16 * wave + 4 * q + r) * 68 + nt * 16 + l15] = cv[nt][r];
    __syncthreads();

    {   // all 64 lanes: (oo-half = lane>>5, vpair = lane&31); 2 rows x 128 B per iter
        const int oo2  = lane >> 5;
        const int vloc = 2 * (lane & 31);
        if (vbase + vloc < NVV) {    // pair {v,v+1}: both valid or both OOB (NVV even)
            unsigned short* prow = pre + (size_t)(b * COUT + 16 * wave) * PSTRIDE + vbase;
            #pragma unroll
            for (int ot = 0; ot < 8; ++ot) {
                const int oo = 2 * ot + oo2;
                float2 t = *(const float2*)(outT + (16 * wave + oo) * 68 + vloc);
                *(unsigned*)(prow + (size_t)oo * PSTRIDE + vloc) = pk2(t.x, t.y);
            }
        }
    }

    if (tid < 64) {
        const int w = tid >> 4, qq = (tid >> 2) & 3, e = tid & 3;
        const int g = 8 * w + 2 * qq + (e >> 1);
        atomicAdd(&stats[b * 64 + 2 * g + (e & 1)], sredA[(w * 4 + qq) * 4 + e]);
    }
}

// grid: 2048 blocks; blk = b + 8*(o + 64*quarter) -> blk%8==b matches k_conv's
// writer XCD (pre[b] rows live in XCD b's L2). Split-stream: read bf16 pre, write f32 out.
__global__ __launch_bounds__(256) void k_norm(
    const unsigned short* __restrict__ pre,
    float* __restrict__ out,
    const float* __restrict__ stats,
    const float* __restrict__ gamma,
    const float* __restrict__ beta)
{
    const int blk     = blockIdx.x;
    const int b       = blk & 7;
    const int rest    = blk >> 3;               // 0..255
    const int o       = rest & 63;
    const int quarter = rest >> 6;
    const int row     = b * 64 + o;
    const int g = o >> 1;
    const float inv_cnt = 1.f / (float)(2 * NVV);
    const float mean = stats[b * 64 + 2 * g] * inv_cnt;
    const float var  = fmaf(stats[b * 64 + 2 * g + 1], inv_cnt, -mean * mean);
    const float rs   = rsqrtf(var + EPSV);
    const float sc   = gamma[o] * rs;
    const float sh   = fmaf(-mean, sc, beta[o]);

    const uint4* src = (const uint4*)(pre + (size_t)row * PSTRIDE);
    float* orow = out + (size_t)row * NVV;
    #pragma unroll
    for (int it = 0; it < 5; ++it) {            // 4 quarters x 5 x 256 = 5120 uint4 = v<40960
        const int c = quarter * 1280 + it * 256 + (int)threadIdx.x;
        uint4 u = src[c];
        float f[8] = { bflo(u.x), bfhi(u.x), bflo(u.y), bfhi(u.y),
                       bflo(u.z), bfhi(u.z), bflo(u.w), bfhi(u.w) };
        float* p = orow + 8 * c;                // 32B-aligned
        float4 o0, o1;
        float y;
        y = fmaf(f[0], sc, sh); o0.x = y > 0.f ? y : 0.f;
        y = fmaf(f[1], sc, sh); o0.y = y > 0.f ? y : 0.f;
        y = fmaf(f[2], sc, sh); o0.z = y > 0.f ? y : 0.f;
        y = fmaf(f[3], sc, sh); o0.w = y > 0.f ? y : 0.f;
        y = fmaf(f[4], sc, sh); o1.x = y > 0.f ? y : 0.f;
        y = fmaf(f[5], sc, sh); o1.y = y > 0.f ? y : 0.f;
        y = fmaf(f[6], sc, sh); o1.z = y > 0.f ? y : 0.f;
        y = fmaf(f[7], sc, sh); o1.w = y > 0.f ? y : 0.f;
        *(float4*)(p)     = o0;                 // 2 x dwordx4 stores
        *(float4*)(p + 4) = o1;
    }
    if (quarter == 3 && threadIdx.x == 0) {     // tail v = 40960, 40961
        unsigned u = *(const unsigned*)(pre + (size_t)row * PSTRIDE + 40960);
        float y0 = fmaf(bflo(u), sc, sh);
        float y1 = fmaf(bfhi(u), sc, sh);
        *(float2*)(orow + 40960) = make_float2(y0 > 0.f ? y0 : 0.f, y1 > 0.f ? y1 : 0.f);
    }
}

extern "C" void kernel_launch(void* const* d_in, const int* in_sizes, int n_in,
                              void* d_out, int out_size, void* d_ws, size_t ws_size,
                              hipStream_t stream) {
    const float* x      = (const float*)d_in[0];
    const float* Lw     = (const float*)d_in[1];
    const float* Ew     = (const float*)d_in[2];
    const float* Nw     = (const float*)d_in[3];
    const float* coeffs = (const float*)d_in[4];
    const float* bias   = (const float*)d_in[5];
    const float* gamma  = (const float*)d_in[6];
    const float* beta   = (const float*)d_in[7];
    const int*   nbr    = (const int*)d_in[8];
    float* out = (float*)d_out;
    float*          stats = (float*)d_ws;
    unsigned short* cW    = (unsigned short*)((char*)d_ws + CW_OFF);
    unsigned short* xT    = (unsigned short*)((char*)d_ws + XT_OFF);
    unsigned short* pre   = (unsigned short*)((char*)d_ws + PRE_OFF);
    uint4*          W4    = (uint4*)((char*)d_ws + W4_OFF);            // needs ws >= ~57.2 MB

    k_tr<<<dim3(161, BB), dim3(256), 0, stream>>>(x, xT, coeffs, cW, stats, Lw, Ew, Nw, nbr, W4);

    k_conv<<<dim3(BB * NTILE), dim3(256), 0, stream>>>(xT, W4, cW, bias, pre, stats);

    k_norm<<<dim3(4 * BB * COUT), dim3(256), 0, stream>>>(pre, out, stats, gamma, beta);
}